// Round 1
// baseline (47909.540 us; speedup 1.0000x reference)
//
#include <hip/hip_runtime.h>

#define HID 50
#define SEQT 512

__device__ __forceinline__ float fast_rcp(float x) { return __builtin_amdgcn_rcpf(x); }
__device__ __forceinline__ float sigm(float x) { return fast_rcp(1.f + __expf(-x)); }
// tanh(x) = 1 - 2/(exp(2x)+1); exp overflow -> inf -> rcp(inf)=0 -> 1.0 (correct saturation)
__device__ __forceinline__ float tanh_f(float x) { return 1.f - 2.f * fast_rcp(__expf(2.f * x) + 1.f); }

__global__ __launch_bounds__(64, 4) void lstm2_fused(
    const float* __restrict__ x,
    const float* __restrict__ Wih0, const float* __restrict__ Whh0,
    const float* __restrict__ bih0, const float* __restrict__ bhh0,
    const float* __restrict__ Wih1, const float* __restrict__ Whh1,
    const float* __restrict__ bih1, const float* __restrict__ bhh1,
    const float* __restrict__ Wfc,  const float* __restrict__ bfc,
    float* __restrict__ out)
{
    const int b = blockIdx.x;
    const int j = threadIdx.x;          // hidden unit; 0..49 active
    const bool act = j < HID;
    const int jc = act ? j : 0;

    __shared__ float2 h0s2[32];
    __shared__ float2 h1s2[32];
    float* h0s = (float*)h0s2;
    float* h1s = (float*)h1s2;
    h0s[j] = 0.f;
    h1s[j] = 0.f;

    // Hoist biases (b_ih + b_hh), input-weight rows (K=3), and recurrent row ptrs.
    // Gate order i|f|g|o: rows j, 50+j, 100+j, 150+j.
    float bsum0[4], bsum1[4], wx0[4], wx1[4], wx2[4];
    const float2* W0r[4];
    const float2* W1i[4];
    const float2* W1r[4];
#pragma unroll
    for (int g = 0; g < 4; ++g) {
        const int r = g * HID + jc;
        bsum0[g] = bih0[r] + bhh0[r];
        bsum1[g] = bih1[r] + bhh1[r];
        wx0[g] = Wih0[r * 3 + 0];
        wx1[g] = Wih0[r * 3 + 1];
        wx2[g] = Wih0[r * 3 + 2];
        W0r[g] = (const float2*)(Whh0 + r * HID);  // rows are 50 floats = 200B -> 8B aligned
        W1i[g] = (const float2*)(Wih1 + r * HID);
        W1r[g] = (const float2*)(Whh1 + r * HID);
    }
    __syncthreads();

    const float* xb = x + (size_t)b * (SEQT * 3);
    float h1v = 0.f, c0 = 0.f, c1 = 0.f;

    for (int t = 0; t < SEQT; ++t) {
        // ----- layer 0 -----
        const float xv0 = xb[0], xv1 = xb[1], xv2 = xb[2];
        xb += 3;
        float a0 = bsum0[0] + wx0[0] * xv0 + wx1[0] * xv1 + wx2[0] * xv2;
        float a1 = bsum0[1] + wx0[1] * xv0 + wx1[1] * xv1 + wx2[1] * xv2;
        float a2 = bsum0[2] + wx0[2] * xv0 + wx1[2] * xv1 + wx2[2] * xv2;
        float a3 = bsum0[3] + wx0[3] * xv0 + wx1[3] * xv1 + wx2[3] * xv2;
#pragma unroll 5
        for (int k = 0; k < HID / 2; ++k) {
            const float2 hv = h0s2[k];
            float2 w;
            w = W0r[0][k]; a0 += w.x * hv.x; a0 += w.y * hv.y;
            w = W0r[1][k]; a1 += w.x * hv.x; a1 += w.y * hv.y;
            w = W0r[2][k]; a2 += w.x * hv.x; a2 += w.y * hv.y;
            w = W0r[3][k]; a3 += w.x * hv.x; a3 += w.y * hv.y;
        }
        const float i0 = sigm(a0), f0 = sigm(a1), g0 = tanh_f(a2), o0 = sigm(a3);
        c0 = f0 * c0 + i0 * g0;
        const float h0v = o0 * tanh_f(c0);
        __syncthreads();                 // all lanes done reading old h0s
        h0s[j] = act ? h0v : 0.f;
        __syncthreads();

        // ----- layer 1 (input = h0s, recurrent = h1s) -----
        a0 = bsum1[0]; a1 = bsum1[1]; a2 = bsum1[2]; a3 = bsum1[3];
#pragma unroll 5
        for (int k = 0; k < HID / 2; ++k) {
            const float2 hv0 = h0s2[k];
            const float2 hv1 = h1s2[k];
            float2 w;
            w = W1i[0][k]; a0 += w.x * hv0.x; a0 += w.y * hv0.y;
            w = W1r[0][k]; a0 += w.x * hv1.x; a0 += w.y * hv1.y;
            w = W1i[1][k]; a1 += w.x * hv0.x; a1 += w.y * hv0.y;
            w = W1r[1][k]; a1 += w.x * hv1.x; a1 += w.y * hv1.y;
            w = W1i[2][k]; a2 += w.x * hv0.x; a2 += w.y * hv0.y;
            w = W1r[2][k]; a2 += w.x * hv1.x; a2 += w.y * hv1.y;
            w = W1i[3][k]; a3 += w.x * hv0.x; a3 += w.y * hv0.y;
            w = W1r[3][k]; a3 += w.x * hv1.x; a3 += w.y * hv1.y;
        }
        const float i1 = sigm(a0), f1 = sigm(a1), g1 = tanh_f(a2), o1 = sigm(a3);
        c1 = f1 * c1 + i1 * g1;
        h1v = o1 * tanh_f(c1);
        __syncthreads();                 // all lanes done reading old h1s
        h1s[j] = act ? h1v : 0.f;
        __syncthreads();
    }

    // ----- FC head: out[b] = sum_j h1[j]*Wfc[j] + bfc -----
    float v = act ? h1v * Wfc[jc] : 0.f;
#pragma unroll
    for (int off = 32; off > 0; off >>= 1) v += __shfl_down(v, off, 64);
    if (j == 0) out[b] = v + bfc[0];
}

extern "C" void kernel_launch(void* const* d_in, const int* in_sizes, int n_in,
                              void* d_out, int out_size, void* d_ws, size_t ws_size,
                              hipStream_t stream)
{
    const float* x    = (const float*)d_in[0];
    const float* Wih0 = (const float*)d_in[1];
    const float* Whh0 = (const float*)d_in[2];
    const float* bih0 = (const float*)d_in[3];
    const float* bhh0 = (const float*)d_in[4];
    const float* Wih1 = (const float*)d_in[5];
    const float* Whh1 = (const float*)d_in[6];
    const float* bih1 = (const float*)d_in[7];
    const float* bhh1 = (const float*)d_in[8];
    const float* Wfc  = (const float*)d_in[9];
    const float* bfc  = (const float*)d_in[10];
    float* out = (float*)d_out;

    const int B = in_sizes[0] / (SEQT * 3);
    lstm2_fused<<<B, 64, 0, stream>>>(x, Wih0, Whh0, bih0, bhh0,
                                      Wih1, Whh1, bih1, bhh1, Wfc, bfc, out);
}

// Round 2
// 907.779 us; speedup vs baseline: 52.7767x; 52.7767x over previous
//
#include <hip/hip_runtime.h>

#define SEQT 512
#define BM 16     // batch rows per block
#define TPW 4     // gate-tiles per wave (4 waves x 4 tiles = 16 tiles = 256 gate rows, 200 real)

typedef _Float16 half8 __attribute__((ext_vector_type(8)));
typedef float f32x4 __attribute__((ext_vector_type(4)));

__device__ __forceinline__ float fast_rcp(float x) { return __builtin_amdgcn_rcpf(x); }
__device__ __forceinline__ float sigm(float x) { return fast_rcp(1.f + __expf(-x)); }
// tanh via exp; saturates correctly at +/-inf
__device__ __forceinline__ float tanh_f(float x) { return 1.f - 2.f * fast_rcp(__expf(2.f * x) + 1.f); }

// Gate-row permutation: logical MFMA row n = 4*u + g  (u = hidden unit, g = gate i|f|g|o).
// C-fragment: row = (lane>>4)*4 + reg, col = lane&15  => lane (tile T) holds gates r=0..3 of
// unit u = T*4 + (lane>>4) for batch m = lane&15. Zero cross-lane exchange for activations.

__global__ __launch_bounds__(256, 1) void lstm2_mfma(
    const float* __restrict__ x,
    const float* __restrict__ Wih0, const float* __restrict__ Whh0,
    const float* __restrict__ bih0, const float* __restrict__ bhh0,
    const float* __restrict__ Wih1, const float* __restrict__ Whh1,
    const float* __restrict__ bih1, const float* __restrict__ bhh1,
    const float* __restrict__ Wfc,  const float* __restrict__ bfc,
    float* __restrict__ out)
{
    // h-state staged for MFMA B-operand: [batch m][k], fp16, XOR-swizzled.
    // hB0: k 0-63 = h0_hi (real 0-49), k 64-127 = h0_lo.
    // hB1: k 0-63 = h0_hi, 64-127 = h1_hi, 128-191 = h0_lo, 192-255 = h1_lo.
    __shared__ __align__(16) _Float16 hB0[BM * 128];
    __shared__ __align__(16) _Float16 hB1[BM * 256];
    __shared__ float fcbuf[4][BM];

    const int tid = threadIdx.x;
    const int l   = tid & 63;
    const int w   = tid >> 6;
    const int m   = l & 15;      // batch col (C col, B col, A row index base)
    const int g4  = l >> 4;      // lane group 0..3
    const int b0  = blockIdx.x * BM;
    const int swz = (m & 7) << 4;

    for (int i = tid; i < BM * 128 / 2; i += 256) ((int*)hB0)[i] = 0;
    for (int i = tid; i < BM * 256 / 2; i += 256) ((int*)hB1)[i] = 0;

    // ---------------- stage weights into per-lane A-fragments (once) ----------------
    // A-frag lane mapping (16x16x32): row = lane&15, k = (lane>>4)*8 + j  (j=0..7)
    half8 a0[TPW][2];   // layer0: W_hh0, K=50 pad 64 -> 2 k-tiles
    half8 a1[TPW][4];   // layer1: k 0-63 = W_ih1 (vs h0), k 64-127 = W_hh1 (vs h1)
    float xw[TPW][4][3], bs0[TPW][4], bs1[TPW][4], wfcv[TPW];

#pragma unroll
    for (int tt = 0; tt < TPW; ++tt) {
        const int T  = w * TPW + tt;          // global gate-tile 0..15
        // --- per-lane C-row params (activations): unit u = T*4 + g4, gates r=0..3
        const int u  = T * 4 + g4;
        const bool ur = u < 50;
#pragma unroll
        for (int r = 0; r < 4; ++r) {
            const int orig = r * 50 + (ur ? u : 0);
            bs0[tt][r] = ur ? (bih0[orig] + bhh0[orig]) : 0.f;
            bs1[tt][r] = ur ? (bih1[orig] + bhh1[orig]) : 0.f;
#pragma unroll
            for (int i = 0; i < 3; ++i) xw[tt][r][i] = ur ? Wih0[orig * 3 + i] : 0.f;
        }
        wfcv[tt] = ur ? Wfc[u] : 0.f;

        // --- A-fragment rows: n = T*16 + m
        const int nA = T * 16 + m;
        const int uA = nA >> 2, gA = nA & 3;
        const bool uAr = uA < 50;
        const int origA = gA * 50 + (uAr ? uA : 0);
#pragma unroll
        for (int kt = 0; kt < 2; ++kt) {
            half8 v;
#pragma unroll
            for (int j = 0; j < 8; ++j) {
                const int k = kt * 32 + g4 * 8 + j;
                const float f = (uAr && k < 50) ? Whh0[origA * 50 + k] : 0.f;
                v[j] = (_Float16)f;
            }
            a0[tt][kt] = v;
        }
#pragma unroll
        for (int kt = 0; kt < 4; ++kt) {
            half8 v;
#pragma unroll
            for (int j = 0; j < 8; ++j) {
                const int k = kt * 32 + g4 * 8 + j;
                float f = 0.f;
                if (uAr) {
                    if (k < 50)                    f = Wih1[origA * 50 + k];
                    else if (k >= 64 && k < 114)   f = Whh1[origA * 50 + (k - 64)];
                }
                v[j] = (_Float16)f;
            }
            a1[tt][kt] = v;
        }
    }

    float c0[TPW], c1[TPW], h1v[TPW];
#pragma unroll
    for (int tt = 0; tt < TPW; ++tt) { c0[tt] = 0.f; c1[tt] = 0.f; h1v[tt] = 0.f; }

    const int uW = 0;  (void)uW;
    const float* xb = x + (size_t)(b0 + m) * SEQT * 3;

    __syncthreads();   // LDS zeros visible

    for (int t = 0; t < SEQT; ++t) {
        // -------- phase 0: load B-frags of h0_{t-1} (+ x for this step) --------
        half8 bf0[4];
#pragma unroll
        for (int q = 0; q < 4; ++q) {   // q=0,1: h0_hi k-tiles; q=2,3: h0_lo
            int byte = m * 256 + (q * 32 + g4 * 8) * 2;
            byte ^= swz;
            bf0[q] = *(const half8*)((const char*)hB0 + byte);
        }
        const float xv0 = xb[t * 3 + 0], xv1 = xb[t * 3 + 1], xv2 = xb[t * 3 + 2];

        __syncthreads();   // all B0 reads done before h0 overwrite

        // -------- phase 1: layer 0 --------
#pragma unroll
        for (int tt = 0; tt < TPW; ++tt) {
            f32x4 acc;
#pragma unroll
            for (int r = 0; r < 4; ++r)
                acc[r] = bs0[tt][r] + xw[tt][r][0] * xv0 + xw[tt][r][1] * xv1 + xw[tt][r][2] * xv2;
#pragma unroll
            for (int kt = 0; kt < 2; ++kt) {
                acc = __builtin_amdgcn_mfma_f32_16x16x32_f16(a0[tt][kt], bf0[kt],     acc, 0, 0, 0);
                acc = __builtin_amdgcn_mfma_f32_16x16x32_f16(a0[tt][kt], bf0[kt + 2], acc, 0, 0, 0);
            }
            const float gi = sigm(acc[0]), gf = sigm(acc[1]);
            const float gg = tanh_f(acc[2]), go = sigm(acc[3]);
            const float c  = gf * c0[tt] + gi * gg;
            c0[tt] = c;
            const float h  = go * tanh_f(c);
            const _Float16 hh = (_Float16)h;
            const _Float16 hl = (_Float16)(h - (float)hh);
            const int u = (w * TPW + tt) * 4 + g4;   // 0..63 (pad units write zeros)
            *(_Float16*)((char*)hB0 + ((m * 256 + u * 2)          ^ swz)) = hh;
            *(_Float16*)((char*)hB0 + ((m * 256 + (64 + u) * 2)   ^ swz)) = hl;
            *(_Float16*)((char*)hB1 + ((m * 512 + u * 2)          ^ swz)) = hh;
            *(_Float16*)((char*)hB1 + ((m * 512 + (128 + u) * 2)  ^ swz)) = hl;
        }

        __syncthreads();   // h0_t visible in hB1

        // -------- phase 2: load B-frags for layer 1 (h0_t | h1_{t-1}) --------
        half8 bf1[8];
#pragma unroll
        for (int q = 0; q < 8; ++q) {   // q 0-3: hi (h0|h1), q 4-7: lo
            int byte = m * 512 + (q * 32 + g4 * 8) * 2;
            byte ^= swz;
            bf1[q] = *(const half8*)((const char*)hB1 + byte);
        }

        __syncthreads();   // all B1 reads done before h1 overwrite

        // -------- phase 3: layer 1 --------
#pragma unroll
        for (int tt = 0; tt < TPW; ++tt) {
            f32x4 acc;
#pragma unroll
            for (int r = 0; r < 4; ++r) acc[r] = bs1[tt][r];
#pragma unroll
            for (int kt = 0; kt < 4; ++kt) {
                acc = __builtin_amdgcn_mfma_f32_16x16x32_f16(a1[tt][kt], bf1[kt],     acc, 0, 0, 0);
                acc = __builtin_amdgcn_mfma_f32_16x16x32_f16(a1[tt][kt], bf1[kt + 4], acc, 0, 0, 0);
            }
            const float gi = sigm(acc[0]), gf = sigm(acc[1]);
            const float gg = tanh_f(acc[2]), go = sigm(acc[3]);
            const float c  = gf * c1[tt] + gi * gg;
            c1[tt] = c;
            const float h  = go * tanh_f(c);
            h1v[tt] = h;
            const _Float16 hh = (_Float16)h;
            const _Float16 hl = (_Float16)(h - (float)hh);
            const int u = (w * TPW + tt) * 4 + g4;
            *(_Float16*)((char*)hB1 + ((m * 512 + (64 + u) * 2)   ^ swz)) = hh;
            *(_Float16*)((char*)hB1 + ((m * 512 + (192 + u) * 2)  ^ swz)) = hl;
        }
        // next iteration's phase-0 barrier protects hB0/hB1 write/read ordering
    }

    // ---------------- FC head: out[b] = sum_u h1[u] * Wfc[u] + bfc ----------------
    float p = 0.f;
#pragma unroll
    for (int tt = 0; tt < TPW; ++tt) p += h1v[tt] * wfcv[tt];   // wfcv=0 for pad units
    p += __shfl_down(p, 32, 64);
    p += __shfl_down(p, 16, 64);
    if (l < 16) fcbuf[w][l] = p;
    __syncthreads();
    if (tid < 16) {
        out[b0 + tid] = fcbuf[0][tid] + fcbuf[1][tid] + fcbuf[2][tid] + fcbuf[3][tid] + bfc[0];
    }
}

extern "C" void kernel_launch(void* const* d_in, const int* in_sizes, int n_in,
                              void* d_out, int out_size, void* d_ws, size_t ws_size,
                              hipStream_t stream)
{
    const float* x    = (const float*)d_in[0];
    const float* Wih0 = (const float*)d_in[1];
    const float* Whh0 = (const float*)d_in[2];
    const float* bih0 = (const float*)d_in[3];
    const float* bhh0 = (const float*)d_in[4];
    const float* Wih1 = (const float*)d_in[5];
    const float* Whh1 = (const float*)d_in[6];
    const float* bih1 = (const float*)d_in[7];
    const float* bhh1 = (const float*)d_in[8];
    const float* Wfc  = (const float*)d_in[9];
    const float* bfc  = (const float*)d_in[10];
    float* out = (float*)d_out;

    const int B = in_sizes[0] / (SEQT * 3);   // 4096
    lstm2_mfma<<<B / BM, 256, 0, stream>>>(x, Wih0, Whh0, bih0, bhh0,
                                           Wih1, Whh1, bih1, bhh1, Wfc, bfc, out);
}

// Round 3
// 771.436 us; speedup vs baseline: 62.1044x; 1.1767x over previous
//
#include <hip/hip_runtime.h>

#define SEQT 512
#define BM   16          // batch rows per block (MFMA N)
#define TPW  2           // gate-tiles per wave
#define NW   8           // waves per block
#define NT   (NW * 64)
#define HB0_BUF 4096     // 16 rows * 128 k * 2B
#define HB1_BUF 8192     // 16 rows * 256 k * 2B

typedef _Float16 half8  __attribute__((ext_vector_type(8)));
typedef _Float16 half2v __attribute__((ext_vector_type(2)));
typedef float    f32x4  __attribute__((ext_vector_type(4)));

__device__ __forceinline__ float fast_rcp(float x) { return __builtin_amdgcn_rcpf(x); }
__device__ __forceinline__ float sigm(float x) { return fast_rcp(1.f + __expf(-x)); }
// tanh via exp; saturates correctly (exp->inf -> rcp->0 -> 1)
__device__ __forceinline__ float tanh_f(float x) { return 1.f - 2.f * fast_rcp(__expf(2.f * x) + 1.f); }

struct __align__(16) Smem {
    char hB0[2 * HB0_BUF];   // [buf][m][k0..127]  k=2u hi, 2u+1 lo   (h0 state)
    char hB1[2 * HB1_BUF];   // [buf][m][k0..255]  k<128: h0 interleaved, k>=128: h1 interleaved
    float fcbuf[NW][BM];
};

// Gate-row permutation: MFMA row n = 4*u + g (u=unit, g=gate i|f|g|o).
// C-frag: row=(lane>>4)*4+reg, col=lane&15 -> lane holds all 4 gates of one unit for one batch.
// A-frag: row=lane&15, k=(lane>>4)*8+j.  B-frag: k=(lane>>4)*8+j, col=lane&15.

__global__ __launch_bounds__(NT, 2) void lstm2_mfma2(
    const float* __restrict__ x,
    const float* __restrict__ Wih0, const float* __restrict__ Whh0,
    const float* __restrict__ bih0, const float* __restrict__ bhh0,
    const float* __restrict__ Wih1, const float* __restrict__ Whh1,
    const float* __restrict__ bih1, const float* __restrict__ bhh1,
    const float* __restrict__ Wfc,  const float* __restrict__ bfc,
    float* __restrict__ out)
{
    __shared__ Smem sm;
    const int tid = threadIdx.x;
    const int l   = tid & 63, w = tid >> 6;
    const int m   = l & 15,  g4 = l >> 4;
    const int b0  = blockIdx.x * BM;
    const int swz = (m & 7) << 4;
    const bool wReal = (w < 7);          // waves 7: tiles 14,15 are pure pad

    // zero ALL h buffers once: pad-unit slots must stay 0 forever (A=0 there, but 0xAA->NaN must never enter)
    for (int i = tid; i < (2 * HB0_BUF + 2 * HB1_BUF) / 4; i += NT)
        ((int*)sm.hB0)[i] = 0;

    // ---------------- stage weights into per-lane A-fragments (once) ----------------
    half8 a0[TPW][4];    // L0: W_hh0 over interleaved k (128): k=2u,2u+1 -> same W[.,u]
    half8 a1[TPW][8];    // L1: k<128 W_ih1 interleaved, k>=128 W_hh1 interleaved
    float bs0[TPW][4], bs1[TPW][4], xw[TPW][4][3], wfcv[TPW];

#pragma unroll
    for (int tt = 0; tt < TPW; ++tt) {
        const int T  = w * TPW + tt;
        const int uc = T * 4 + g4;            // this lane's C-row unit
        const bool ucr = uc < 50;
#pragma unroll
        for (int r = 0; r < 4; ++r) {
            const int orig = r * 50 + (ucr ? uc : 0);
            bs0[tt][r] = ucr ? (bih0[orig] + bhh0[orig]) : 0.f;
            bs1[tt][r] = ucr ? (bih1[orig] + bhh1[orig]) : 0.f;
#pragma unroll
            for (int i = 0; i < 3; ++i) xw[tt][r][i] = ucr ? Wih0[orig * 3 + i] : 0.f;
        }
        wfcv[tt] = ucr ? Wfc[uc] : 0.f;

        const int nA = T * 16 + m;            // A-frag row
        const int uA = nA >> 2, gA = nA & 3;
        const bool uAr = uA < 50;
        const int origA = gA * 50 + (uAr ? uA : 0);
#pragma unroll
        for (int kt = 0; kt < 4; ++kt) {
            half8 v;
#pragma unroll
            for (int j = 0; j < 8; ++j) {
                const int k = kt * 32 + g4 * 8 + j;
                const int u = k >> 1;
                v[j] = (_Float16)((uAr && u < 50) ? Whh0[origA * 50 + u] : 0.f);
            }
            a0[tt][kt] = v;
        }
#pragma unroll
        for (int kt = 0; kt < 8; ++kt) {
            half8 v;
#pragma unroll
            for (int j = 0; j < 8; ++j) {
                const int k = kt * 32 + g4 * 8 + j;
                float f = 0.f;
                if (uAr) {
                    if (k < 128) { const int u = k >> 1;        if (u < 50) f = Wih1[origA * 50 + u]; }
                    else         { const int u = (k - 128) >> 1; if (u < 50) f = Whh1[origA * 50 + u]; }
                }
                v[j] = (_Float16)f;
            }
            a1[tt][kt] = v;
        }
    }

    // ---------------- loop-invariant LDS byte addresses ----------------
    const char* p0[4]; const char* p1[8];
    char *pw0[TPW], *pw1a[TPW], *pw1b[TPW];
#pragma unroll
    for (int q = 0; q < 4; ++q) p0[q] = sm.hB0 + ((m * 256 + q * 64 + g4 * 16) ^ swz);
#pragma unroll
    for (int q = 0; q < 8; ++q) p1[q] = sm.hB1 + ((m * 512 + q * 64 + g4 * 16) ^ swz);
#pragma unroll
    for (int tt = 0; tt < TPW; ++tt) {
        const int u = (w * TPW + tt) * 4 + g4;
        pw0[tt]  = (char*)sm.hB0 + ((m * 256 + u * 4) ^ swz);          // h0 -> hB0[next]
        pw1a[tt] = (char*)sm.hB1 + ((m * 512 + u * 4) ^ swz);          // h0 -> hB1[cur].h0sec
        pw1b[tt] = (char*)sm.hB1 + ((m * 512 + 256 + u * 4) ^ swz);    // h1 -> hB1[next].h1sec
    }

    float c0[TPW] = {0.f, 0.f}, c1[TPW] = {0.f, 0.f}, h1v[TPW] = {0.f, 0.f};
    const float4* xb4 = (const float4*)(x + (size_t)(b0 + m) * SEQT * 3);

    __syncthreads();   // LDS zeros visible

    for (int t4 = 0; t4 < SEQT / 4; ++t4) {
        float xs[12];
        if (wReal) {   // 4 timesteps of x (12 floats), aligned dwordx4 loads
            const float4 q0 = xb4[t4 * 3 + 0], q1 = xb4[t4 * 3 + 1], q2 = xb4[t4 * 3 + 2];
            xs[0] = q0.x; xs[1] = q0.y; xs[2]  = q0.z; xs[3]  = q0.w;
            xs[4] = q1.x; xs[5] = q1.y; xs[6]  = q1.z; xs[7]  = q1.w;
            xs[8] = q2.x; xs[9] = q2.y; xs[10] = q2.z; xs[11] = q2.w;
        }
#pragma unroll
        for (int sub = 0; sub < 4; ++sub) {
            const int cur = sub & 1;
            const int o0r = cur * HB0_BUF,  o0w = (1 - cur) * HB0_BUF;
            const int o1r = cur * HB1_BUF,  o1w = (1 - cur) * HB1_BUF;

            // -------- layer 0 --------
            if (wReal) {
                half8 bf0[4];
#pragma unroll
                for (int q = 0; q < 4; ++q) bf0[q] = *(const half8*)(p0[q] + o0r);
                const float xv0 = xs[sub * 3], xv1 = xs[sub * 3 + 1], xv2 = xs[sub * 3 + 2];
#pragma unroll
                for (int tt = 0; tt < TPW; ++tt) {
                    if ((w * TPW + tt) * 4 >= 50) continue;   // wave-uniform pad-tile skip
                    f32x4 acc;
#pragma unroll
                    for (int r = 0; r < 4; ++r)
                        acc[r] = bs0[tt][r] + xw[tt][r][0] * xv0 + xw[tt][r][1] * xv1 + xw[tt][r][2] * xv2;
#pragma unroll
                    for (int kt = 0; kt < 4; ++kt)
                        acc = __builtin_amdgcn_mfma_f32_16x16x32_f16(a0[tt][kt], bf0[kt], acc, 0, 0, 0);
                    const float gi = sigm(acc[0]), gf = sigm(acc[1]);
                    const float gg = tanh_f(acc[2]), go = sigm(acc[3]);
                    const float c = gf * c0[tt] + gi * gg; c0[tt] = c;
                    const float h = go * tanh_f(c);
                    const _Float16 hh = (_Float16)h;
                    const _Float16 hl = (_Float16)(h - (float)hh);
                    half2v pk; pk[0] = hh; pk[1] = hl;
                    *(half2v*)(pw0[tt]  + o0w) = pk;
                    *(half2v*)(pw1a[tt] + o1r) = pk;
                }
            }
            __syncthreads();   // the ONE barrier: h0(t) visible for L1(t); orders all other hazards too

            // -------- layer 1 --------
            if (wReal) {
                half8 bf1[8];
#pragma unroll
                for (int q = 0; q < 8; ++q) bf1[q] = *(const half8*)(p1[q] + o1r);
#pragma unroll
                for (int tt = 0; tt < TPW; ++tt) {
                    if ((w * TPW + tt) * 4 >= 50) continue;
                    f32x4 acc;
#pragma unroll
                    for (int r = 0; r < 4; ++r) acc[r] = bs1[tt][r];
#pragma unroll
                    for (int kt = 0; kt < 8; ++kt)
                        acc = __builtin_amdgcn_mfma_f32_16x16x32_f16(a1[tt][kt], bf1[kt], acc, 0, 0, 0);
                    const float gi = sigm(acc[0]), gf = sigm(acc[1]);
                    const float gg = tanh_f(acc[2]), go = sigm(acc[3]);
                    const float c = gf * c1[tt] + gi * gg; c1[tt] = c;
                    const float h = go * tanh_f(c);
                    h1v[tt] = h;
                    const _Float16 hh = (_Float16)h;
                    const _Float16 hl = (_Float16)(h - (float)hh);
                    half2v pk; pk[0] = hh; pk[1] = hl;
                    *(half2v*)(pw1b[tt] + o1w) = pk;
                }
            }
            // no barrier here: L0(t+1) touches only hB0/hB1[h0sec] slots whose last
            // cross-wave access was before the barrier above (see hazard analysis)
        }
    }

    // ---------------- FC head ----------------
    float p = h1v[0] * wfcv[0] + h1v[1] * wfcv[1];   // pad lanes/waves contribute 0
    p += __shfl_down(p, 32, 64);
    p += __shfl_down(p, 16, 64);
    if (l < 16) sm.fcbuf[w][l] = p;
    __syncthreads();
    if (tid < BM) {
        float s = bfc[0];
#pragma unroll
        for (int ww = 0; ww < NW; ++ww) s += sm.fcbuf[ww][tid];
        out[b0 + tid] = s;
    }
}

extern "C" void kernel_launch(void* const* d_in, const int* in_sizes, int n_in,
                              void* d_out, int out_size, void* d_ws, size_t ws_size,
                              hipStream_t stream)
{
    const float* x    = (const float*)d_in[0];
    const float* Wih0 = (const float*)d_in[1];
    const float* Whh0 = (const float*)d_in[2];
    const float* bih0 = (const float*)d_in[3];
    const float* bhh0 = (const float*)d_in[4];
    const float* Wih1 = (const float*)d_in[5];
    const float* Whh1 = (const float*)d_in[6];
    const float* bih1 = (const float*)d_in[7];
    const float* bhh1 = (const float*)d_in[8];
    const float* Wfc  = (const float*)d_in[9];
    const float* bfc  = (const float*)d_in[10];
    float* out = (float*)d_out;

    const int B = in_sizes[0] / (SEQT * 3);   // 4096
    lstm2_mfma2<<<B / BM, NT, 0, stream>>>(x, Wih0, Whh0, bih0, bhh0,
                                           Wih1, Whh1, bih1, bhh1, Wfc, bfc, out);
}

// Round 4
// 687.029 us; speedup vs baseline: 69.7344x; 1.1229x over previous
//
#include <hip/hip_runtime.h>

#define SEQT 512
#define BM   16           // batch rows per block (MFMA N)
#define NW   13           // waves per block = gate-tiles (13 x 16 = 208 rows >= 200)
#define NT   (NW * 64)
#define HBUF 8192         // one h buffer: 16 rows * 256 k * 2B  (k<128: h0 interleaved hi/lo, k>=128: h1)

typedef _Float16 half8  __attribute__((ext_vector_type(8)));
typedef _Float16 half2v __attribute__((ext_vector_type(2)));
typedef float    f32x4  __attribute__((ext_vector_type(4)));

__device__ __forceinline__ float fast_rcp(float x) { return __builtin_amdgcn_rcpf(x); }
__device__ __forceinline__ float sigm(float x) { return fast_rcp(1.f + __expf(-x)); }
// tanh via exp; saturates correctly (exp->inf -> rcp->0 -> 1)
__device__ __forceinline__ float tanh_f(float x) { return 1.f - 2.f * fast_rcp(__expf(2.f * x) + 1.f); }

struct __align__(16) Smem {
    char hB[2 * HBUF];        // double-buffered merged h-state
    float fcbuf[NW][BM];
};

// Gate-row permutation: MFMA row n = 4*u + g (u=unit, g=gate i|f|g|o).
// C-frag: row=(lane>>4)*4+reg, col=lane&15 -> lane holds all 4 gates of one unit for one batch.
// A-frag: row=lane&15, k=(lane>>4)*8+j.  B-frag: k=(lane>>4)*8+j, col=lane&15.
// k-layout (interleaved hi/lo): k=2u -> h_hi(u), k=2u+1 -> h_lo(u); A duplicates W[.,u] at both k.
// Buffer parity p=t&1: L0 reads buf[1-p].h0, writes h0(t)->buf[p].h0;
//                      L1 reads buf[p] (h0(t)|h1(t-1)), writes h1(t)->buf[1-p].h1.
// Single barrier per timestep (between L0 and L1) separates every RAW/WAR pair.

__global__ __launch_bounds__(NT) void lstm2_mfma3(
    const float* __restrict__ x,
    const float* __restrict__ Wih0, const float* __restrict__ Whh0,
    const float* __restrict__ bih0, const float* __restrict__ bhh0,
    const float* __restrict__ Wih1, const float* __restrict__ Whh1,
    const float* __restrict__ bih1, const float* __restrict__ bhh1,
    const float* __restrict__ Wfc,  const float* __restrict__ bfc,
    float* __restrict__ out)
{
    __shared__ Smem sm;
    const int tid = threadIdx.x;
    const int l   = tid & 63, w = tid >> 6;      // w = gate-tile T, 0..12
    const int m   = l & 15,  g4 = l >> 4;
    const int b0  = blockIdx.x * BM;
    const int swz = (m & 7) << 4;

    // zero both h buffers: pad slots (u>=50) must stay 0 forever
    for (int i = tid; i < 2 * HBUF / 4; i += NT) ((int*)sm.hB)[i] = 0;

    // ---------------- stage weights into per-lane A-fragments (once) ----------------
    half8 a0[4];    // L0: W_hh0, interleaved k (K=128)
    half8 a1[8];    // L1: k<128 W_ih1 interleaved, k>=128 W_hh1 interleaved (K=256)
    float bs0[4], bs1[4], xw[4][3], wfcv;

    {
        const int uc = w * 4 + g4;               // this lane's C-row unit
        const bool ucr = uc < 50;
#pragma unroll
        for (int r = 0; r < 4; ++r) {
            const int orig = r * 50 + (ucr ? uc : 0);
            bs0[r] = ucr ? (bih0[orig] + bhh0[orig]) : 0.f;
            bs1[r] = ucr ? (bih1[orig] + bhh1[orig]) : 0.f;
#pragma unroll
            for (int i = 0; i < 3; ++i) xw[r][i] = ucr ? Wih0[orig * 3 + i] : 0.f;
        }
        wfcv = ucr ? Wfc[uc] : 0.f;

        const int nA = w * 16 + m;               // A-frag row
        const int uA = nA >> 2, gA = nA & 3;
        const bool uAr = uA < 50;
        const int origA = gA * 50 + (uAr ? uA : 0);
#pragma unroll
        for (int kt = 0; kt < 4; ++kt) {
            half8 v;
#pragma unroll
            for (int j = 0; j < 8; ++j) {
                const int k = kt * 32 + g4 * 8 + j;
                const int u = k >> 1;
                v[j] = (_Float16)((uAr && u < 50) ? Whh0[origA * 50 + u] : 0.f);
            }
            a0[kt] = v;
        }
#pragma unroll
        for (int kt = 0; kt < 8; ++kt) {
            half8 v;
#pragma unroll
            for (int j = 0; j < 8; ++j) {
                const int k = kt * 32 + g4 * 8 + j;
                float f = 0.f;
                if (uAr) {
                    if (k < 128) { const int u = k >> 1;         if (u < 50) f = Wih1[origA * 50 + u]; }
                    else         { const int u = (k - 128) >> 1; if (u < 50) f = Whh1[origA * 50 + u]; }
                }
                v[j] = (_Float16)f;
            }
            a1[kt] = v;
        }
    }

    // ---------------- loop-invariant LDS byte offsets ----------------
    int rd[8];          // shared by L0 (q<4, h0 section) and L1 (q<8)
#pragma unroll
    for (int q = 0; q < 8; ++q) rd[q] = (m * 512 + q * 64 + g4 * 16) ^ swz;
    const int uW  = w * 4 + g4;                          // 0..51; pads write h=0 (harmless)
    const int wr0 = (m * 512 + uW * 4) ^ swz;            // h0 slot (k=2u,2u+1)
    const int wr1 = (m * 512 + 256 + uW * 4) ^ swz;      // h1 slot

    float c0 = 0.f, c1 = 0.f, h1v = 0.f;
    const float4* xb4 = (const float4*)(x + (size_t)(b0 + m) * SEQT * 3);

    __syncthreads();   // LDS zeros visible

    for (int t4 = 0; t4 < SEQT / 4; ++t4) {
        // 4 timesteps of x (12 floats), aligned dwordx4 loads
        const float4 q0 = xb4[t4 * 3 + 0], q1 = xb4[t4 * 3 + 1], q2 = xb4[t4 * 3 + 2];
        const float xs[12] = { q0.x, q0.y, q0.z, q0.w, q1.x, q1.y, q1.z, q1.w, q2.x, q2.y, q2.z, q2.w };
#pragma unroll
        for (int sub = 0; sub < 4; ++sub) {
            const int p = sub & 1;
            const int oR0 = (1 - p) * HBUF;   // L0 reads h0(t-1)
            const int oW0 = p * HBUF;         // L0 writes h0(t)
            const int oR1 = p * HBUF;         // L1 reads h0(t)|h1(t-1)
            const int oW1 = (1 - p) * HBUF;   // L1 writes h1(t)

            // -------- layer 0 --------
            {
                half8 bf[4];
#pragma unroll
                for (int q = 0; q < 4; ++q) bf[q] = *(const half8*)(sm.hB + oR0 + rd[q]);
                f32x4 acc;
                const float xv0 = xs[sub * 3], xv1 = xs[sub * 3 + 1], xv2 = xs[sub * 3 + 2];
#pragma unroll
                for (int r = 0; r < 4; ++r)
                    acc[r] = bs0[r] + xw[r][0] * xv0 + xw[r][1] * xv1 + xw[r][2] * xv2;
#pragma unroll
                for (int kt = 0; kt < 4; ++kt)
                    acc = __builtin_amdgcn_mfma_f32_16x16x32_f16(a0[kt], bf[kt], acc, 0, 0, 0);
                const float gi = sigm(acc[0]), gf = sigm(acc[1]);
                const float gg = tanh_f(acc[2]), go = sigm(acc[3]);
                const float c = gf * c0 + gi * gg; c0 = c;
                const float h = go * tanh_f(c);
                const _Float16 hh = (_Float16)h;
                const _Float16 hl = (_Float16)(h - (float)hh);
                half2v pk; pk[0] = hh; pk[1] = hl;
                *(half2v*)(sm.hB + oW0 + wr0) = pk;
            }
            __syncthreads();   // the ONE barrier: h0(t) visible for L1(t); orders all cross-step hazards

            // -------- layer 1 --------
            {
                half8 bf[8];
#pragma unroll
                for (int q = 0; q < 8; ++q) bf[q] = *(const half8*)(sm.hB + oR1 + rd[q]);
                f32x4 acc;
#pragma unroll
                for (int r = 0; r < 4; ++r) acc[r] = bs1[r];
#pragma unroll
                for (int kt = 0; kt < 8; ++kt)
                    acc = __builtin_amdgcn_mfma_f32_16x16x32_f16(a1[kt], bf[kt], acc, 0, 0, 0);
                const float gi = sigm(acc[0]), gf = sigm(acc[1]);
                const float gg = tanh_f(acc[2]), go = sigm(acc[3]);
                const float c = gf * c1 + gi * gg; c1 = c;
                const float h = go * tanh_f(c);
                h1v = h;
                const _Float16 hh = (_Float16)h;
                const _Float16 hl = (_Float16)(h - (float)hh);
                half2v pk; pk[0] = hh; pk[1] = hl;
                *(half2v*)(sm.hB + oW1 + wr1) = pk;
            }
            // no trailing barrier: L0(t+1) touches only slots whose last cross-wave
            // access is separated by the barrier above (hazard table in header comment)
        }
    }

    // ---------------- FC head: out[b] = sum_u h1[u]*Wfc[u] + bfc ----------------
    float pv = h1v * wfcv;                 // pad lanes contribute 0
    pv += __shfl_down(pv, 32, 64);
    pv += __shfl_down(pv, 16, 64);
    if (l < 16) sm.fcbuf[w][l] = pv;
    __syncthreads();
    if (tid < BM) {
        float s = bfc[0];
#pragma unroll
        for (int ww = 0; ww < NW; ++ww) s += sm.fcbuf[ww][tid];
        out[b0 + tid] = s;
    }
}

extern "C" void kernel_launch(void* const* d_in, const int* in_sizes, int n_in,
                              void* d_out, int out_size, void* d_ws, size_t ws_size,
                              hipStream_t stream)
{
    const float* x    = (const float*)d_in[0];
    const float* Wih0 = (const float*)d_in[1];
    const float* Whh0 = (const float*)d_in[2];
    const float* bih0 = (const float*)d_in[3];
    const float* bhh0 = (const float*)d_in[4];
    const float* Wih1 = (const float*)d_in[5];
    const float* Whh1 = (const float*)d_in[6];
    const float* bih1 = (const float*)d_in[7];
    const float* bhh1 = (const float*)d_in[8];
    const float* Wfc  = (const float*)d_in[9];
    const float* bfc  = (const float*)d_in[10];
    float* out = (float*)d_out;

    const int B = in_sizes[0] / (SEQT * 3);   // 4096
    lstm2_mfma3<<<B / BM, NT, 0, stream>>>(x, Wih0, Whh0, bih0, bhh0,
                                           Wih1, Whh1, bih1, bhh1, Wfc, bfc, out);
}

// Round 5
// 566.191 us; speedup vs baseline: 84.6173x; 1.2134x over previous
//
#include <hip/hip_runtime.h>

#define SEQT 512
#define BM   16           // batch rows per block (MFMA N)
#define NW   13           // waves = gate-tiles (13 x 16 = 208 rows >= 200)
#define NT   (NW * 64)
#define ROWB 256          // bytes per batch-row: 128 k-slots * 2B
#define HBUF 4096         // one buffer: 16 rows * 256B

typedef _Float16 half8  __attribute__((ext_vector_type(8)));
typedef _Float16 half4v __attribute__((ext_vector_type(4)));
typedef float    f32x4  __attribute__((ext_vector_type(4)));

__device__ __forceinline__ float fast_rcp(float x) { return __builtin_amdgcn_rcpf(x); }
__device__ __forceinline__ float sigm(float x) { return fast_rcp(1.f + __expf(-x)); }
// tanh via exp; saturates correctly (exp->inf -> rcp->0 -> 1)
__device__ __forceinline__ float tanh_f(float x) { return 1.f - 2.f * fast_rcp(__expf(2.f * x) + 1.f); }

#define MFMA16(A, B, C) __builtin_amdgcn_mfma_f32_16x16x32_f16((A), (B), (C), 0, 0, 0)

// k-layout of one h-buffer row (128 fp16 slots per batch m):
//   k 0..49   h0 units            k 52..54  x_t (fp16)      k 55  constant 1.0
//   k 64..113 h1 units            everything else 0 (A is 0 there too)
// W-split: W = Whi + Wlo (fp16 pair, exact); each B-frag feeds hi-chain AND lo-chain.
// Phase t: L0(t) || L1(t-1). Both read buf[(t+1)&1] (h0(t-1), x(t), h1(t-2)),
// both write buf[t&1] (h0(t), h1(t-1), x(t+1)). ONE barrier per phase.
// C-frag: row=(lane>>4)*4+reg, col=lane&15; gate-row perm n=4u+g -> lane holds
// gates i|f|g|o of unit uc=w*4+g4 for batch m. A-frag: row=lane&15, k=(lane>>4)*8+j.

__global__ __launch_bounds__(NT) void lstm2_mfma4(
    const float* __restrict__ x,
    const float* __restrict__ Wih0, const float* __restrict__ Whh0,
    const float* __restrict__ bih0, const float* __restrict__ bhh0,
    const float* __restrict__ Wih1, const float* __restrict__ Whh1,
    const float* __restrict__ bih1, const float* __restrict__ bhh1,
    const float* __restrict__ Wfc,  const float* __restrict__ bfc,
    float* __restrict__ out)
{
    __shared__ __align__(16) char hb[2 * HBUF];
    __shared__ float fcbuf[NW][BM];

    const int tid = threadIdx.x;
    const int l   = tid & 63, w = tid >> 6;      // w = gate-tile 0..12
    const int m   = l & 15,  g4 = l >> 4;
    const int b0  = blockIdx.x * BM;
    const int swz = (m & 7) << 4;

    // ---------------- A-fragments: W hi/lo split (exact), bias+x folded in ----------------
    half8 a0h[2], a0l[2];    // L0: K=64  (Whh0 | x-cols | bias-col)
    half8 a1h[4], a1l[4];    // L1: K=128 (Wih1 | bias-col | Whh1)
    {
        const int nA = w * 16 + m;               // A-frag gate-row
        const int uA = nA >> 2, gA = nA & 3;
        const bool ok = uA < 50;
        const int rA = gA * 50 + (ok ? uA : 0);
#pragma unroll
        for (int kt = 0; kt < 2; ++kt) {
            half8 vh, vl;
#pragma unroll
            for (int j = 0; j < 8; ++j) {
                const int k = kt * 32 + g4 * 8 + j;
                float f = 0.f;
                if (ok) {
                    if (k < 50)                    f = Whh0[rA * 50 + k];
                    else if (k >= 52 && k < 55)    f = Wih0[rA * 3 + (k - 52)];
                    else if (k == 55)              f = bih0[rA] + bhh0[rA];
                }
                const _Float16 hi = (_Float16)f;
                vh[j] = hi; vl[j] = (_Float16)(f - (float)hi);
            }
            a0h[kt] = vh; a0l[kt] = vl;
        }
#pragma unroll
        for (int kt = 0; kt < 4; ++kt) {
            half8 vh, vl;
#pragma unroll
            for (int j = 0; j < 8; ++j) {
                const int k = kt * 32 + g4 * 8 + j;
                float f = 0.f;
                if (ok) {
                    if (k < 50)                          f = Wih1[rA * 50 + k];
                    else if (k == 55)                    f = bih1[rA] + bhh1[rA];
                    else if (k >= 64 && k < 114)         f = Whh1[rA * 50 + (k - 64)];
                }
                const _Float16 hi = (_Float16)f;
                vh[j] = hi; vl[j] = (_Float16)(f - (float)hi);
            }
            a1h[kt] = vh; a1l[kt] = vl;
        }
    }
    const int uc = w * 4 + g4;                   // this lane's output unit (pad if >=50)
    const float wfcv = (uc < 50) ? Wfc[uc] : 0.f;

    // ---------------- loop-invariant LDS byte offsets (swizzle: XOR bits 6:4 by m&7) ----------------
    int rd[4];
#pragma unroll
    for (int q = 0; q < 4; ++q) rd[q] = m * ROWB + (((q * 4 + g4) * 16) ^ swz);
    const int wr0 = m * ROWB + ((uc * 2) ^ swz);            // h0 slot k=uc
    const int wr1 = m * ROWB + (((64 + uc) * 2) ^ swz);     // h1 slot k=64+uc
    const int wrx = m * ROWB + (104 ^ swz);                 // x slots k=52..55 (8B aligned)

    // ---------------- init: zero both buffers, plant x(0) and the 1.0 column ----------------
    for (int i = tid; i < 2 * HBUF / 4; i += NT) ((int*)hb)[i] = 0;
    __syncthreads();
    const bool xlane = (w == 0) && (g4 == 0);    // 16 lanes, m = batch
    const float* xbase = x + (size_t)(b0 + m) * (SEQT * 3);
    const _Float16 onef = (_Float16)1.f;
    if (xlane) {
        half4v xv;
        xv[0] = (_Float16)xbase[0]; xv[1] = (_Float16)xbase[1];
        xv[2] = (_Float16)xbase[2]; xv[3] = onef;
        *(half4v*)(hb + HBUF + wrx) = xv;        // buf1: x(0) + 1.0  (phase 0 reads buf1)
        half4v z; z[0] = (_Float16)0.f; z[1] = z[0]; z[2] = z[0]; z[3] = onef;
        *(half4v*)(hb + wrx) = z;                // buf0: 1.0 column
    }
    float c0 = 0.f, c1 = 0.f, h1v = 0.f;
    __syncthreads();

    const f32x4 z4 = {0.f, 0.f, 0.f, 0.f};

    // ---------------- one phase: L0(t) || L1(t-1), single barrier ----------------
    auto phase = [&](int rb, int wb, bool doL1, bool doX, int t) {
        const half8 bf0 = *(const half8*)(hb + rb + rd[0]);
        const half8 bf1 = *(const half8*)(hb + rb + rd[1]);
        const half8 bf2 = *(const half8*)(hb + rb + rd[2]);
        const half8 bf3 = *(const half8*)(hb + rb + rd[3]);

        // L0(t): 2 independent chains (hi, lo) over K=64
        f32x4 aH = MFMA16(a0h[0], bf0, z4); aH = MFMA16(a0h[1], bf1, aH);
        f32x4 aL = MFMA16(a0l[0], bf0, z4); aL = MFMA16(a0l[1], bf1, aL);

        // L1(t-1): 2 independent chains over K=128 (reuses bf0..bf3)
        f32x4 g1v;
        if (doL1) {
            f32x4 bH = MFMA16(a1h[0], bf0, z4); bH = MFMA16(a1h[1], bf1, bH);
            bH = MFMA16(a1h[2], bf2, bH);       bH = MFMA16(a1h[3], bf3, bH);
            f32x4 bL = MFMA16(a1l[0], bf0, z4); bL = MFMA16(a1l[1], bf1, bL);
            bL = MFMA16(a1l[2], bf2, bL);       bL = MFMA16(a1l[3], bf3, bL);
            g1v = bH + bL;
        }
        const f32x4 g0v = aH + aL;

        // L0 activations -> h0(t)
        const float i0 = sigm(g0v[0]), f0 = sigm(g0v[1]);
        const float gg0 = tanh_f(g0v[2]), o0 = sigm(g0v[3]);
        c0 = f0 * c0 + i0 * gg0;
        const float h0 = o0 * tanh_f(c0);
        *(_Float16*)(hb + wb + wr0) = (_Float16)h0;

        if (doL1) {  // L1 activations -> h1(t-1)
            const float i1 = sigm(g1v[0]), f1 = sigm(g1v[1]);
            const float gg1 = tanh_f(g1v[2]), o1 = sigm(g1v[3]);
            c1 = f1 * c1 + i1 * gg1;
            h1v = o1 * tanh_f(c1);
            *(_Float16*)(hb + wb + wr1) = (_Float16)h1v;
        }
        if (doX && xlane) {                      // stage x(t+1) into the write buffer
            const float* xp = xbase + (t + 1) * 3;
            half4v xv;
            xv[0] = (_Float16)xp[0]; xv[1] = (_Float16)xp[1];
            xv[2] = (_Float16)xp[2]; xv[3] = onef;
            *(half4v*)(hb + wb + wrx) = xv;
        }
        __syncthreads();
    };

    // phase 0: L0(0) only
    phase(HBUF, 0, false, true, 0);
    // phases 1..510
    for (int it = 0; it < 255; ++it) {
        phase(0, HBUF, true, true, 2 * it + 1);
        phase(HBUF, 0, true, true, 2 * it + 2);
    }
    // phase 511 (no x(512) to stage)
    phase(0, HBUF, true, false, 511);

    // epilogue: L1(511), reads buf1 (h0(511), h1(510)); no writes needed
    {
        const half8 bf0 = *(const half8*)(hb + HBUF + rd[0]);
        const half8 bf1 = *(const half8*)(hb + HBUF + rd[1]);
        const half8 bf2 = *(const half8*)(hb + HBUF + rd[2]);
        const half8 bf3 = *(const half8*)(hb + HBUF + rd[3]);
        f32x4 bH = MFMA16(a1h[0], bf0, z4); bH = MFMA16(a1h[1], bf1, bH);
        bH = MFMA16(a1h[2], bf2, bH);       bH = MFMA16(a1h[3], bf3, bH);
        f32x4 bL = MFMA16(a1l[0], bf0, z4); bL = MFMA16(a1l[1], bf1, bL);
        bL = MFMA16(a1l[2], bf2, bL);       bL = MFMA16(a1l[3], bf3, bL);
        const f32x4 g1v = bH + bL;
        const float i1 = sigm(g1v[0]), f1 = sigm(g1v[1]);
        const float gg1 = tanh_f(g1v[2]), o1 = sigm(g1v[3]);
        c1 = f1 * c1 + i1 * gg1;
        h1v = o1 * tanh_f(c1);
    }

    // ---------------- FC head: out[b] = sum_u h1[u]*Wfc[u] + bfc ----------------
    float pv = h1v * wfcv;                       // pad lanes contribute 0
    pv += __shfl_down(pv, 32, 64);
    pv += __shfl_down(pv, 16, 64);
    if (l < 16) fcbuf[w][l] = pv;
    __syncthreads();
    if (tid < BM) {
        float s = bfc[0];
#pragma unroll
        for (int ww = 0; ww < NW; ++ww) s += fcbuf[ww][tid];
        out[b0 + tid] = s;
    }
}

extern "C" void kernel_launch(void* const* d_in, const int* in_sizes, int n_in,
                              void* d_out, int out_size, void* d_ws, size_t ws_size,
                              hipStream_t stream)
{
    const float* x    = (const float*)d_in[0];
    const float* Wih0 = (const float*)d_in[1];
    const float* Whh0 = (const float*)d_in[2];
    const float* bih0 = (const float*)d_in[3];
    const float* bhh0 = (const float*)d_in[4];
    const float* Wih1 = (const float*)d_in[5];
    const float* Whh1 = (const float*)d_in[6];
    const float* bih1 = (const float*)d_in[7];
    const float* bhh1 = (const float*)d_in[8];
    const float* Wfc  = (const float*)d_in[9];
    const float* bfc  = (const float*)d_in[10];
    float* out = (float*)d_out;

    const int B = in_sizes[0] / (SEQT * 3);   // 4096
    lstm2_mfma4<<<B / BM, NT, 0, stream>>>(x, Wih0, Whh0, bih0, bhh0,
                                           Wih1, Whh1, bih1, bhh1, Wfc, bfc, out);
}

// Round 7
// 540.144 us; speedup vs baseline: 88.6977x; 1.0482x over previous
//
#include <hip/hip_runtime.h>

#define SEQT 512
#define BM   16           // batch rows per block (MFMA N)
#define NW   7            // waves; wave w owns gate-tiles 2w, 2w+1 (tile 13 = pad)
#define NT   (NW * 64)    // 448 threads
#define ROWB 256          // bytes per batch-row: 128 k-slots * 2B
#define HBUF 4096         // one buffer: 16 rows * 256B

typedef _Float16 half8  __attribute__((ext_vector_type(8)));
typedef _Float16 half4v __attribute__((ext_vector_type(4)));
typedef float    f32x4  __attribute__((ext_vector_type(4)));

__device__ __forceinline__ float fast_rcp(float x) { return __builtin_amdgcn_rcpf(x); }
__device__ __forceinline__ float sigm(float x) { return fast_rcp(1.f + __expf(-x)); }
// tanh via exp; saturates correctly (exp->inf -> rcp->0 -> 1)
__device__ __forceinline__ float tanh_f(float x) { return 1.f - 2.f * fast_rcp(__expf(2.f * x) + 1.f); }

#define MFMA16(A, B, C) __builtin_amdgcn_mfma_f32_16x16x32_f16((A), (B), (C), 0, 0, 0)

// k-layout of one h-buffer row (128 fp16 slots per batch m):
//   k 0..49  h0 units   k 52..54 x_t   k 55 const 1.0   k 64..113 h1 units   else 0
// Single-fp16 W (no hi/lo). Phase t: L0(t) || L1(t-1); both read buf[rb], write buf[wb];
// ONE barrier per phase. B-fragment is gate-tile-independent -> 4 ds_read_b128 serve
// both tiles and both layers.
// C-frag: row=(lane>>4)*4+reg, col=lane&15; gate-perm n=4u+g -> lane holds gates
// i|f|g|o of unit uc=T*4+g4 for batch m. A-frag: row=lane&15, k=(lane>>4)*8+j.

__global__ __launch_bounds__(NT) void lstm2_mfma5(
    const float* __restrict__ x,
    const float* __restrict__ Wih0, const float* __restrict__ Whh0,
    const float* __restrict__ bih0, const float* __restrict__ bhh0,
    const float* __restrict__ Wih1, const float* __restrict__ Whh1,
    const float* __restrict__ bih1, const float* __restrict__ bhh1,
    const float* __restrict__ Wfc,  const float* __restrict__ bfc,
    float* __restrict__ out)
{
    __shared__ __align__(16) char hb[2 * HBUF];
    __shared__ float fcbuf[NW][BM];

    const int tid = threadIdx.x;
    const int l   = tid & 63, w = tid >> 6;      // w = wave 0..6
    const int m   = l & 15,  g4 = l >> 4;
    const int b0  = blockIdx.x * BM;
    const int swz = (m & 7) << 4;
    const bool hasT1 = (w < 6);                  // tile 2w+1 real iff < 13

    // ---------------- A-fragments (single fp16), two tiles ----------------
    half8 a0[2][2];      // L0: K=64  (Whh0 | x-cols 52..54 | bias-col 55)
    half8 a1[2][4];      // L1: K=128 (Wih1 | bias-col 55 | Whh1 at 64..113)
    float wfcv[2];
    int   ucv[2];
    bool  wok[2];
#pragma unroll
    for (int tt = 0; tt < 2; ++tt) {
        const int T  = 2 * w + tt;
        const int nA = T * 16 + m;               // A-frag gate-row
        const int uA = nA >> 2, gA = nA & 3;
        const bool ok = uA < 50;
        const int rA = gA * 50 + (ok ? uA : 0);
#pragma unroll
        for (int kt = 0; kt < 2; ++kt) {
            half8 v;
#pragma unroll
            for (int j = 0; j < 8; ++j) {
                const int k = kt * 32 + g4 * 8 + j;
                float f = 0.f;
                if (ok) {
                    if (k < 50)                 f = Whh0[rA * 50 + k];
                    else if (k >= 52 && k < 55) f = Wih0[rA * 3 + (k - 52)];
                    else if (k == 55)           f = bih0[rA] + bhh0[rA];
                }
                v[j] = (_Float16)f;
            }
            a0[tt][kt] = v;
        }
#pragma unroll
        for (int kt = 0; kt < 4; ++kt) {
            half8 v;
#pragma unroll
            for (int j = 0; j < 8; ++j) {
                const int k = kt * 32 + g4 * 8 + j;
                float f = 0.f;
                if (ok) {
                    if (k < 50)                  f = Wih1[rA * 50 + k];
                    else if (k == 55)            f = bih1[rA] + bhh1[rA];
                    else if (k >= 64 && k < 114) f = Whh1[rA * 50 + (k - 64)];
                }
                v[j] = (_Float16)f;
            }
            a1[tt][kt] = v;
        }
        const int uc = T * 4 + g4;               // this lane's output unit for tile tt
        ucv[tt]  = uc;
        wok[tt]  = (uc < 50);                    // pads must NOT write (k 52..55 = x/bias!)
        wfcv[tt] = (uc < 50) ? Wfc[uc] : 0.f;
    }

    // ---------------- loop-invariant LDS byte offsets ----------------
    int rd[4], wr0[2], wr1[2];
#pragma unroll
    for (int q = 0; q < 4; ++q) rd[q] = m * ROWB + (((q * 4 + g4) * 16) ^ swz);
#pragma unroll
    for (int tt = 0; tt < 2; ++tt) {
        wr0[tt] = m * ROWB + ((ucv[tt] * 2) ^ swz);          // h0 slot k=uc
        wr1[tt] = m * ROWB + (((64 + ucv[tt]) * 2) ^ swz);   // h1 slot k=64+uc
    }
    const int wrx = m * ROWB + (104 ^ swz);                  // x slots k=52..55 (8B)

    // ---------------- init: zero buffers, plant x(0) and the 1.0 column ----------------
    for (int i = tid; i < 2 * HBUF / 4; i += NT) ((int*)hb)[i] = 0;
    __syncthreads();
    const bool xlane = (w == 0) && (g4 == 0);    // 16 lanes, m = batch
    const float* xbase = x + (size_t)(b0 + m) * (SEQT * 3);
    const _Float16 onef = (_Float16)1.f;
    if (xlane) {
        half4v xv;
        xv[0] = (_Float16)xbase[0]; xv[1] = (_Float16)xbase[1];
        xv[2] = (_Float16)xbase[2]; xv[3] = onef;
        *(half4v*)(hb + HBUF + wrx) = xv;        // buf1: x(0)+1.0 (phase 0 reads buf1)
        half4v z; z[0] = (_Float16)0.f; z[1] = z[0]; z[2] = z[0]; z[3] = onef;
        *(half4v*)(hb + wrx) = z;                // buf0: 1.0 column
    }
    float c0[2] = {0.f, 0.f}, c1[2] = {0.f, 0.f}, h1v[2] = {0.f, 0.f};
    __syncthreads();

    const f32x4 z4 = {0.f, 0.f, 0.f, 0.f};

    // ---------------- one phase: L0(t) || L1(t-1), single barrier ----------------
    auto phase = [&](int rb, int wb, bool doL1, bool doX, int t) {
        const half8 bf0 = *(const half8*)(hb + rb + rd[0]);
        const half8 bf1 = *(const half8*)(hb + rb + rd[1]);
        const half8 bf2 = *(const half8*)(hb + rb + rd[2]);
        const half8 bf3 = *(const half8*)(hb + rb + rd[3]);

        // ---- MFMAs first: up to 6 independent chains of depth <= 2 ----
        f32x4 gA0, gA1, gB0, gB1;
        gA0 = MFMA16(a0[0][0], bf0, z4); gA0 = MFMA16(a0[0][1], bf1, gA0);
        if (hasT1) { gA1 = MFMA16(a0[1][0], bf0, z4); gA1 = MFMA16(a0[1][1], bf1, gA1); }
        if (doL1) {
            f32x4 p = MFMA16(a1[0][0], bf0, z4); p = MFMA16(a1[0][1], bf1, p);
            f32x4 q = MFMA16(a1[0][2], bf2, z4); q = MFMA16(a1[0][3], bf3, q);
            gB0 = p + q;
            if (hasT1) {
                f32x4 r = MFMA16(a1[1][0], bf0, z4); r = MFMA16(a1[1][1], bf1, r);
                f32x4 s = MFMA16(a1[1][2], bf2, z4); s = MFMA16(a1[1][3], bf3, s);
                gB1 = r + s;
            }
        }

        // ---- activations: tile 0 then tile 1 (independent chains) ----
#pragma unroll
        for (int tt = 0; tt < 2; ++tt) {
            if (tt == 1 && !hasT1) break;
            const f32x4 g0v = (tt == 0) ? gA0 : gA1;
            const float i0 = sigm(g0v[0]), f0 = sigm(g0v[1]);
            const float gg0 = tanh_f(g0v[2]), o0 = sigm(g0v[3]);
            c0[tt] = f0 * c0[tt] + i0 * gg0;
            const float h0 = o0 * tanh_f(c0[tt]);
            if (wok[tt]) *(_Float16*)(hb + wb + wr0[tt]) = (_Float16)h0;
            if (doL1) {
                const f32x4 g1v = (tt == 0) ? gB0 : gB1;
                const float i1 = sigm(g1v[0]), f1 = sigm(g1v[1]);
                const float gg1 = tanh_f(g1v[2]), o1 = sigm(g1v[3]);
                c1[tt] = f1 * c1[tt] + i1 * gg1;
                h1v[tt] = o1 * tanh_f(c1[tt]);
                if (wok[tt]) *(_Float16*)(hb + wb + wr1[tt]) = (_Float16)h1v[tt];
            }
        }
        if (doX && xlane) {                      // stage x(t+1) into the write buffer
            const float* xp = xbase + (t + 1) * 3;
            half4v xv;
            xv[0] = (_Float16)xp[0]; xv[1] = (_Float16)xp[1];
            xv[2] = (_Float16)xp[2]; xv[3] = onef;
            *(half4v*)(hb + wb + wrx) = xv;
        }
        __syncthreads();
    };

    // phase 0: L0(0) only
    phase(HBUF, 0, false, true, 0);
    // phases 1..510
    for (int it = 0; it < 255; ++it) {
        phase(0, HBUF, true, true, 2 * it + 1);
        phase(HBUF, 0, true, true, 2 * it + 2);
    }
    // phase 511 (no x(512) to stage)
    phase(0, HBUF, true, false, 511);

    // epilogue: L1(511) reads buf1 (h0(511), h1(510)); no writes needed
    {
        const half8 bf0 = *(const half8*)(hb + HBUF + rd[0]);
        const half8 bf1 = *(const half8*)(hb + HBUF + rd[1]);
        const half8 bf2 = *(const half8*)(hb + HBUF + rd[2]);
        const half8 bf3 = *(const half8*)(hb + HBUF + rd[3]);
#pragma unroll
        for (int tt = 0; tt < 2; ++tt) {
            if (tt == 1 && !hasT1) break;
            f32x4 p = MFMA16(a1[tt][0], bf0, z4); p = MFMA16(a1[tt][1], bf1, p);
            f32x4 q = MFMA16(a1[tt][2], bf2, z4); q = MFMA16(a1[tt][3], bf3, q);
            const f32x4 g1v = p + q;
            const float i1 = sigm(g1v[0]), f1 = sigm(g1v[1]);
            const float gg1 = tanh_f(g1v[2]), o1 = sigm(g1v[3]);
            c1[tt] = f1 * c1[tt] + i1 * gg1;
            h1v[tt] = o1 * tanh_f(c1[tt]);
        }
    }

    // ---------------- FC head: out[b] = sum_u h1[u]*Wfc[u] + bfc ----------------
    float pv = h1v[0] * wfcv[0] + h1v[1] * wfcv[1];   // pad lanes contribute 0
    pv += __shfl_down(pv, 32, 64);
    pv += __shfl_down(pv, 16, 64);
    if (l < 16) fcbuf[w][l] = pv;
    __syncthreads();
    if (tid < BM) {
        float s = bfc[0];
#pragma unroll
        for (int ww = 0; ww < NW; ++ww) s += fcbuf[ww][tid];
        out[b0 + tid] = s;
    }
}

extern "C" void kernel_launch(void* const* d_in, const int* in_sizes, int n_in,
                              void* d_out, int out_size, void* d_ws, size_t ws_size,
                              hipStream_t stream)
{
    const float* x    = (const float*)d_in[0];
    const float* Wih0 = (const float*)d_in[1];
    const float* Whh0 = (const float*)d_in[2];
    const float* bih0 = (const float*)d_in[3];
    const float* bhh0 = (const float*)d_in[4];
    const float* Wih1 = (const float*)d_in[5];
    const float* Whh1 = (const float*)d_in[6];
    const float* bih1 = (const float*)d_in[7];
    const float* bhh1 = (const float*)d_in[8];
    const float* Wfc  = (const float*)d_in[9];
    const float* bfc  = (const float*)d_in[10];
    float* out = (float*)d_out;

    const int B = in_sizes[0] / (SEQT * 3);   // 4096
    lstm2_mfma5<<<B / BM, NT, 0, stream>>>(x, Wih0, Whh0, bih0, bhh0,
                                           Wih1, Whh1, bih1, bhh1, Wfc, bfc, out);
}